// Round 1
// 154.107 us; speedup vs baseline: 1.1916x; 1.1916x over previous
//
#include <hip/hip_runtime.h>
#include <stdint.h>

#define NGT 8000
#define NSAMP 4000
#define QT 8         // queries per thread (register tile)
#define QB 2048      // queries per block (256 threads * QT)
#define CH 256       // scanned-points chunk per block (== blockDim)

struct Params {
  const float* gt;        // (8000,3)
  const float* gtn;       // (8000,3)
  const float* pred[3];   // (v,3)
  const float* bef[3];    // (v,3)
  const int*   edges[3];  // (3v,2)
  const int*   faces[3];  // (2v,3)
  const int*   lap[3];    // (v,10)
  float* S[3];            // (4000,3) sampled surface points
  unsigned int* mb1[3];        // (8000) ordered-float min bits (dist1)
  unsigned long long* mb2a[3]; // (v) packed (ordered dist << 32 | gt idx) for pred queries
  unsigned int* mb2b[3];       // (4000) ordered-float min bits for sample queries
  float* acc;             // per mesh i: [8i]=sum_d1 [8i+1]=sum_d2 [8i+2]=sum|dot| [8i+3]=edge_sq [8i+4]=lap_sq [8i+5]=move_sq
  unsigned int* counter;  // finish_kernel block-completion counter
  unsigned int* init_base;// = (u32*)d_ws
  int init_words;         // words to initialize (first 64 -> 0, rest -> 0xFF)
  int prep_init_blocks;   // ceil(init_words/256)
  int v[3], M[3], E[3], F[3];
  int cseg[10];           // chamfer segment starts; seg = role*3 + mesh
  int cnc[9];             // chunks per segment
  int fseg[13];           // finish segment starts; seg = z*3 + mesh
};

// ---- ordered-float <-> uint (monotone, atomicMin-compatible) ----
__device__ __forceinline__ unsigned int ford(float f){
  unsigned int b = __float_as_uint(f);
  return b ^ ((b >> 31) ? 0xFFFFFFFFu : 0x80000000u);
}
__device__ __forceinline__ float funord(unsigned int u){
  unsigned int b = u ^ ((u >> 31) ? 0x80000000u : 0xFFFFFFFFu);
  return __uint_as_float(b);
}

// ---------------- threefry2x32 (exact JAX) ----------------
__device__ __forceinline__ uint32_t rotl32(uint32_t x, int d){ return (x<<d)|(x>>(32-d)); }

__device__ __forceinline__ void tf2x32(uint32_t k0, uint32_t k1, uint32_t c0, uint32_t c1,
                                       uint32_t& o0, uint32_t& o1){
  uint32_t ks2 = k0 ^ k1 ^ 0x1BD11BDAu;
  uint32_t x0 = c0 + k0, x1 = c1 + k1;
  x0+=x1; x1=rotl32(x1,13); x1^=x0;
  x0+=x1; x1=rotl32(x1,15); x1^=x0;
  x0+=x1; x1=rotl32(x1,26); x1^=x0;
  x0+=x1; x1=rotl32(x1, 6); x1^=x0;
  x0+=k1; x1+=ks2+1u;
  x0+=x1; x1=rotl32(x1,17); x1^=x0;
  x0+=x1; x1=rotl32(x1,29); x1^=x0;
  x0+=x1; x1=rotl32(x1,16); x1^=x0;
  x0+=x1; x1=rotl32(x1,24); x1^=x0;
  x0+=ks2; x1+=k0+2u;
  x0+=x1; x1=rotl32(x1,13); x1^=x0;
  x0+=x1; x1=rotl32(x1,15); x1^=x0;
  x0+=x1; x1=rotl32(x1,26); x1^=x0;
  x0+=x1; x1=rotl32(x1, 6); x1^=x0;
  x0+=k0; x1+=k1+3u;
  x0+=x1; x1=rotl32(x1,17); x1^=x0;
  x0+=x1; x1=rotl32(x1,29); x1^=x0;
  x0+=x1; x1=rotl32(x1,16); x1^=x0;
  x0+=x1; x1=rotl32(x1,24); x1^=x0;
  x0+=k1; x1+=ks2+4u;
  x0+=x1; x1=rotl32(x1,13); x1^=x0;
  x0+=x1; x1=rotl32(x1,15); x1^=x0;
  x0+=x1; x1=rotl32(x1,26); x1^=x0;
  x0+=x1; x1=rotl32(x1, 6); x1^=x0;
  x0+=ks2; x1+=k0+5u;
  o0=x0; o1=x1;
}

__device__ __forceinline__ uint32_t rbits(uint32_t k0, uint32_t k1, uint32_t idx, uint32_t total){
  uint32_t half = total>>1, o0, o1;
  if (idx < half){ tf2x32(k0,k1, idx, idx+half, o0, o1); return o0; }
  tf2x32(k0,k1, idx-half, idx, o0, o1); return o1;
}

// ---------------- A: init workspace + sample surface points (1D packed) ----------------
__global__ __launch_bounds__(256) void prep_kernel(Params p){
  int b = blockIdx.x;
  int t = threadIdx.x;
  if (b < p.prep_init_blocks){
    int wdi = b*256 + t;
    if (wdi < p.init_words)
      p.init_base[wdi] = (wdi < 64) ? 0u : 0xFFFFFFFFu;
    return;
  }
  int rem = b - p.prep_init_blocks;   // 16 sample blocks per mesh
  int i = rem >> 4;
  int s = ((rem & 15) << 8) + t;
  if (s >= NSAMP) return;
  uint32_t bk0, bk1; tf2x32(0u, 42u, 0u, (uint32_t)i, bk0, bk1);
  uint32_t ka0,kb0,ka1,kb1;
  tf2x32(bk0,bk1, 0u,2u, ka0,kb0);
  tf2x32(bk0,bk1, 1u,3u, ka1,kb1);
  uint32_t fb = rbits(ka0,ka1,(uint32_t)s, NSAMP);
  uint32_t fidx = fb % (uint32_t)p.F[i];
  uint32_t u0b = rbits(kb0,kb1, 2u*(uint32_t)s,    2u*NSAMP);
  uint32_t u1b = rbits(kb0,kb1, 2u*(uint32_t)s+1u, 2u*NSAMP);
  float u0 = __uint_as_float((u0b>>9)|0x3F800000u) - 1.0f;
  float u1 = __uint_as_float((u1b>>9)|0x3F800000u) - 1.0f;
  float r1 = sqrtf(u0);
  float w0 = 1.0f - r1, w1 = r1*(1.0f-u1), w2 = r1*u1;
  const int* f = p.faces[i] + 3*(int)fidx;
  const float* pr = p.pred[i];
  int va=f[0], vb=f[1], vc=f[2];
  float* dst = p.S[i] + 3*s;
  dst[0] = w0*pr[3*va+0] + w1*pr[3*vb+0] + w2*pr[3*vc+0];
  dst[1] = w0*pr[3*va+1] + w1*pr[3*vb+1] + w2*pr[3*vc+1];
  dst[2] = w0*pr[3*va+2] + w1*pr[3*vb+2] + w2*pr[3*vc+2];
}

// ---------------- B: fused chamfer, packed 1D grid, 3 roles ----------------
__device__ __forceinline__ float dist_e(const float4 g, float qx, float qy, float qz){
  return fmaf(g.x,qx, fmaf(g.y,qy, fmaf(g.z,qz, g.w)));
}

// min-only scan: 8-point register prefetch groups; 8 ds_read then 224 VALU
__device__ __forceinline__ void scan_min(const float4* __restrict__ tile, int lim,
    const float* qx, const float* qy, const float* qz, float* best)
{
  int k = 0;
  int lim8 = lim & ~7;
  for (; k < lim8; k += 8){
    float4 g0=tile[k+0],g1=tile[k+1],g2=tile[k+2],g3=tile[k+3];
    float4 g4=tile[k+4],g5=tile[k+5],g6=tile[k+6],g7=tile[k+7];
    #pragma unroll
    for (int q=0;q<QT;q++){
      float d0=dist_e(g0,qx[q],qy[q],qz[q]);
      float d1=dist_e(g1,qx[q],qy[q],qz[q]);
      float d2=dist_e(g2,qx[q],qy[q],qz[q]);
      float d3=dist_e(g3,qx[q],qy[q],qz[q]);
      float d4=dist_e(g4,qx[q],qy[q],qz[q]);
      float d5=dist_e(g5,qx[q],qy[q],qz[q]);
      float d6=dist_e(g6,qx[q],qy[q],qz[q]);
      float d7=dist_e(g7,qx[q],qy[q],qz[q]);
      float m = fminf(fminf(best[q], d0), d1);  // -> v_min3_f32 chains
      m = fminf(fminf(m, d2), d3);
      m = fminf(fminf(m, d4), d5);
      m = fminf(fminf(m, d6), d7);
      best[q] = m;
    }
  }
  for (; k < lim; k++){
    float4 g = tile[k];
    #pragma unroll
    for (int q=0;q<QT;q++)
      best[q] = fminf(best[q], dist_e(g,qx[q],qy[q],qz[q]));
  }
}

// argmin scan: ascending k + strict '<' keeps first occurrence (JAX argmin semantics)
__device__ __forceinline__ void scan_argmin(const float4* __restrict__ tile, int lim, int c0,
    const float* qx, const float* qy, const float* qz, float* best, int* bidx)
{
  int k = 0;
  int lim4 = lim & ~3;
  for (; k < lim4; k += 4){
    float4 g0=tile[k+0],g1=tile[k+1],g2=tile[k+2],g3=tile[k+3];
    #pragma unroll
    for (int q=0;q<QT;q++){
      float d0=dist_e(g0,qx[q],qy[q],qz[q]);
      float d1=dist_e(g1,qx[q],qy[q],qz[q]);
      float d2=dist_e(g2,qx[q],qy[q],qz[q]);
      float d3=dist_e(g3,qx[q],qy[q],qz[q]);
      if (d0 < best[q]){ best[q]=d0; bidx[q]=c0+k+0; }
      if (d1 < best[q]){ best[q]=d1; bidx[q]=c0+k+1; }
      if (d2 < best[q]){ best[q]=d2; bidx[q]=c0+k+2; }
      if (d3 < best[q]){ best[q]=d3; bidx[q]=c0+k+3; }
    }
  }
  for (; k < lim; k++){
    float4 g = tile[k];
    #pragma unroll
    for (int q=0;q<QT;q++){
      float d = dist_e(g,qx[q],qy[q],qz[q]);
      if (d < best[q]){ best[q]=d; bidx[q]=c0+k; }
    }
  }
}

// role 0: dist1      — queries = gt (8000),  scan P=pred++S chunk
// role 1: dist2-pred — queries = pred (v),   scan gt chunk, argmin tracked
// role 2: dist2-samp — queries = S (4000),   scan gt chunk, min only
__global__ __launch_bounds__(256) void chamfer_kernel(Params p){
  __shared__ float4 tile[CH];
  int b = blockIdx.x;
  int seg = 0;
  #pragma unroll
  for (int s=1;s<9;s++) seg += (b >= p.cseg[s]) ? 1 : 0;
  int rem  = b - p.cseg[seg];
  int nc   = p.cnc[seg];
  int cq   = rem / nc;
  int cc   = rem - cq*nc;
  int role = seg / 3;
  int i    = seg - role*3;
  int t = threadIdx.x;
  int qbase = cq*QB;
  int c0 = cc*CH;
  int v = p.v[i];

  if (role == 0){
    int M = p.M[i];
    int lim = min(M - c0, CH);
    if (t < lim){
      int j = c0 + t;
      const float* src = (j < v) ? (p.pred[i] + 3*j) : (p.S[i] + 3*(j-v));
      float x=src[0], y=src[1], z=src[2];
      tile[t] = make_float4(x,y,z, x*x+y*y+z*z);
    }
    float qx[QT],qy[QT],qz[QT],qs[QT],best[QT];
    #pragma unroll
    for (int k=0;k<QT;k++){
      int q = qbase + t + k*256;
      float x=0.f,y=0.f,z=0.f;
      if (q < NGT){ x=p.gt[3*q]; y=p.gt[3*q+1]; z=p.gt[3*q+2]; }
      qs[k]=x*x+y*y+z*z; qx[k]=-2.f*x; qy[k]=-2.f*y; qz[k]=-2.f*z;
      best[k]=3.4e38f;
    }
    __syncthreads();
    scan_min(tile, lim, qx,qy,qz,best);
    #pragma unroll
    for (int k=0;k<QT;k++){
      int q = qbase + t + k*256;
      if (q < NGT) atomicMin(&p.mb1[i][q], ford(best[k]+qs[k]));
    }
  } else if (role == 1){
    int lim = min(NGT - c0, CH);
    if (t < lim){
      int j = c0 + t;
      float x=p.gt[3*j], y=p.gt[3*j+1], z=p.gt[3*j+2];
      tile[t] = make_float4(x,y,z, x*x+y*y+z*z);
    }
    float qx[QT],qy[QT],qz[QT],qs[QT],best[QT];
    int bidx[QT];
    #pragma unroll
    for (int k=0;k<QT;k++){
      int q = qbase + t + k*256;
      float x=0.f,y=0.f,z=0.f;
      if (q < v){
        const float* src = p.pred[i] + 3*q;
        x=src[0]; y=src[1]; z=src[2];
      }
      qs[k]=x*x+y*y+z*z; qx[k]=-2.f*x; qy[k]=-2.f*y; qz[k]=-2.f*z;
      best[k]=3.4e38f; bidx[k]=0;
    }
    __syncthreads();
    scan_argmin(tile, lim, c0, qx,qy,qz,best,bidx);
    #pragma unroll
    for (int k=0;k<QT;k++){
      int q = qbase + t + k*256;
      if (q < v){
        unsigned long long pk = ((unsigned long long)ford(best[k]+qs[k])<<32) | (unsigned int)bidx[k];
        atomicMin(&p.mb2a[i][q], pk);   // equal dist -> smaller gt idx = first occurrence
      }
    }
  } else {
    int lim = min(NGT - c0, CH);
    if (t < lim){
      int j = c0 + t;
      float x=p.gt[3*j], y=p.gt[3*j+1], z=p.gt[3*j+2];
      tile[t] = make_float4(x,y,z, x*x+y*y+z*z);
    }
    float qx[QT],qy[QT],qz[QT],qs[QT],best[QT];
    #pragma unroll
    for (int k=0;k<QT;k++){
      int q = qbase + t + k*256;
      float x=0.f,y=0.f,z=0.f;
      if (q < NSAMP){
        const float* src = p.S[i] + 3*q;
        x=src[0]; y=src[1]; z=src[2];
      }
      qs[k]=x*x+y*y+z*z; qx[k]=-2.f*x; qy[k]=-2.f*y; qz[k]=-2.f*z;
      best[k]=3.4e38f;
    }
    __syncthreads();
    scan_min(tile, lim, qx,qy,qz,best);
    #pragma unroll
    for (int k=0;k<QT;k++){
      int q = qbase + t + k*256;
      if (q < NSAMP) atomicMin(&p.mb2b[i][q], ford(best[k]+qs[k]));
    }
  }
}

// ---------------- C: reductions + losses + last-block finalize (1D packed) ----------------
// z=0: dist2 sum over M; z=1: dist1 sum over NGT; z=2: edge+normal over E; z=3: lap+move over v
__global__ __launch_bounds__(256) void finish_kernel(Params p, float* out){
  __shared__ float red[256];
  int b = blockIdx.x;
  int seg = 0;
  #pragma unroll
  for (int s=1;s<12;s++) seg += (b >= p.fseg[s]) ? 1 : 0;
  int rem = b - p.fseg[seg];
  int z = seg / 3;
  int i = seg - 3*z;
  int tid = threadIdx.x;
  int gidx = rem*256 + tid;

  if (z == 0){
    int M = p.M[i], v = p.v[i];
    float val = 0.f;
    if (gidx < M){
      if (gidx < v) val = funord((unsigned int)(p.mb2a[i][gidx]>>32));
      else          val = funord(p.mb2b[i][gidx-v]);
    }
    red[tid] = val; __syncthreads();
    for (int s=128;s>0;s>>=1){ if (tid<s) red[tid]+=red[tid+s]; __syncthreads(); }
    if (tid==0 && red[0]!=0.f) atomicAdd(&p.acc[8*i+1], red[0]);
  } else if (z == 1){
    float val = 0.f;
    if (gidx < NGT) val = funord(p.mb1[i][gidx]);
    red[tid] = val; __syncthreads();
    for (int s=128;s>0;s>>=1){ if (tid<s) red[tid]+=red[tid+s]; __syncthreads(); }
    if (tid==0 && red[0]!=0.f) atomicAdd(&p.acc[8*i+0], red[0]);
  } else if (z == 2){
    int E = p.E[i];
    float sq = 0.f, ad = 0.f;
    if (gidx < E){
      int e0 = p.edges[i][2*gidx], e1 = p.edges[i][2*gidx+1];
      const float* pr = p.pred[i];
      float dx = pr[3*e0+0]-pr[3*e1+0];
      float dy = pr[3*e0+1]-pr[3*e1+1];
      float dz = pr[3*e0+2]-pr[3*e1+2];
      sq = dx*dx+dy*dy+dz*dz;
      float inv = 1.0f / fmaxf(sqrtf(sq), 1e-12f);
      int g = (int)(unsigned int)p.mb2a[i][e0];   // argmin gt index (low 32 bits)
      float nx = p.gtn[3*g+0], ny = p.gtn[3*g+1], nz = p.gtn[3*g+2];
      float invg = 1.0f / fmaxf(sqrtf(nx*nx+ny*ny+nz*nz), 1e-12f);
      ad = fabsf((dx*nx+dy*ny+dz*nz)*inv*invg);
    }
    red[tid] = ad; __syncthreads();
    for (int s=128;s>0;s>>=1){ if (tid<s) red[tid]+=red[tid+s]; __syncthreads(); }
    if (tid==0 && red[0]!=0.f) atomicAdd(&p.acc[8*i+2], red[0]);
    __syncthreads();
    red[tid] = sq; __syncthreads();
    for (int s=128;s>0;s>>=1){ if (tid<s) red[tid]+=red[tid+s]; __syncthreads(); }
    if (tid==0 && red[0]!=0.f) atomicAdd(&p.acc[8*i+3], red[0]);
  } else {
    int v = p.v[i];
    float lsq = 0.f, msq = 0.f;
    if (gidx < v){
      const int* L = p.lap[i] + 10*gidx;
      const float* B = p.bef[i];
      const float* R = p.pred[i];
      float cnt = (float)L[9];
      float sb0=0,sb1=0,sb2=0, sp0=0,sp1=0,sp2=0;
      #pragma unroll
      for (int k=0;k<8;k++){
        int id = L[k];
        if (id >= 0){
          sb0 += B[3*id+0]; sb1 += B[3*id+1]; sb2 += B[3*id+2];
          sp0 += R[3*id+0]; sp1 += R[3*id+1]; sp2 += R[3*id+2];
        }
      }
      float lb0 = B[3*gidx+0] - sb0/cnt, lb1 = B[3*gidx+1] - sb1/cnt, lb2 = B[3*gidx+2] - sb2/cnt;
      float lp0 = R[3*gidx+0] - sp0/cnt, lp1 = R[3*gidx+1] - sp1/cnt, lp2 = R[3*gidx+2] - sp2/cnt;
      float d0=lb0-lp0, d1=lb1-lp1, d2=lb2-lp2;
      lsq = d0*d0+d1*d1+d2*d2;
      float m0=B[3*gidx+0]-R[3*gidx+0], m1=B[3*gidx+1]-R[3*gidx+1], m2=B[3*gidx+2]-R[3*gidx+2];
      msq = m0*m0+m1*m1+m2*m2;
    }
    red[tid] = lsq; __syncthreads();
    for (int s=128;s>0;s>>=1){ if (tid<s) red[tid]+=red[tid+s]; __syncthreads(); }
    if (tid==0 && red[0]!=0.f) atomicAdd(&p.acc[8*i+4], red[0]);
    __syncthreads();
    red[tid] = msq; __syncthreads();
    for (int s=128;s>0;s>>=1){ if (tid<s) red[tid]+=red[tid+s]; __syncthreads(); }
    if (tid==0 && red[0]!=0.f) atomicAdd(&p.acc[8*i+5], red[0]);
  }

  __syncthreads();
  if (tid == 0){
    __threadfence();
    unsigned int total = gridDim.x;
    unsigned int old = atomicAdd(p.counter, 1u);
    if (old == total-1){
      __threadfence();
      const float CHAMW[3] = {3000.0f, 3000.0f, 3000.0f};
      const float LAPC[3]  = {0.2f, 1.0f, 1.0f};
      float loss = 0.0f;
      for (int m=0;m<3;m++){
        float a0 = __hip_atomic_load(&p.acc[8*m+0], __ATOMIC_RELAXED, __HIP_MEMORY_SCOPE_AGENT);
        float a1 = __hip_atomic_load(&p.acc[8*m+1], __ATOMIC_RELAXED, __HIP_MEMORY_SCOPE_AGENT);
        float a2 = __hip_atomic_load(&p.acc[8*m+2], __ATOMIC_RELAXED, __HIP_MEMORY_SCOPE_AGENT);
        float a3 = __hip_atomic_load(&p.acc[8*m+3], __ATOMIC_RELAXED, __HIP_MEMORY_SCOPE_AGENT);
        float a4 = __hip_atomic_load(&p.acc[8*m+4], __ATOMIC_RELAXED, __HIP_MEMORY_SCOPE_AGENT);
        float a5 = __hip_atomic_load(&p.acc[8*m+5], __ATOMIC_RELAXED, __HIP_MEMORY_SCOPE_AGENT);
        float ch = CHAMW[m]*(a0/(float)NGT + 0.55f*a1/(float)p.M[m]);
        float nl = a2/(float)p.E[m];
        float el = a3/(float)p.E[m];
        float ll = LAPC[m]*a4/(float)p.v[m];
        float ml = (m>0) ? LAPC[m]*a5/(float)p.v[m] : 0.0f;
        loss += ch + 1500.0f*ll + 50.0f*ml + 359.0f*el + 0.5f*nl;
      }
      out[0] = loss;
    }
  }
}

extern "C" void kernel_launch(void* const* d_in, const int* in_sizes, int n_in,
                              void* d_out, int out_size, void* d_ws, size_t ws_size,
                              hipStream_t stream) {
  Params p;
  p.gt  = (const float*)d_in[0];
  p.gtn = (const float*)d_in[1];
  for (int i=0;i<3;i++){
    p.pred[i]  = (const float*)d_in[2+5*i];
    p.bef[i]   = (const float*)d_in[3+5*i];
    p.edges[i] = (const int*)  d_in[4+5*i];
    p.faces[i] = (const int*)  d_in[5+5*i];
    p.lap[i]   = (const int*)  d_in[6+5*i];
    p.v[i] = in_sizes[2+5*i]/3;
    p.E[i] = in_sizes[4+5*i]/2;
    p.F[i] = in_sizes[5+5*i]/3;
    p.M[i] = p.v[i] + NSAMP;
  }
  // Workspace layout (words):
  //   [0,32)  acc  (zeroed)
  //   [32]    counter (zeroed; zero-region = first 64 words)
  //   [64..)  mb1[3] | mb2a[3] | mb2b[3]   (0xFF-filled)
  //   then    S[3]  (written by prep, no init)
  unsigned int* base = (unsigned int*)d_ws;
  p.acc = (float*)base;
  p.counter = base + 32;
  p.init_base = base;
  unsigned int* w = base + 64;
  for (int i=0;i<3;i++){ p.mb1[i]  = w; w += NGT; }
  for (int i=0;i<3;i++){ p.mb2a[i] = (unsigned long long*)w; w += 2*p.v[i]; }
  for (int i=0;i<3;i++){ p.mb2b[i] = w; w += NSAMP; }
  p.init_words = (int)(w - base);
  for (int i=0;i<3;i++){ p.S[i] = (float*)w; w += NSAMP*3; }

  // chamfer packed segments: seg = role*3 + mesh
  int cnq[9];
  for (int i=0;i<3;i++){
    cnq[0+i] = (NGT + QB-1)/QB;           p.cnc[0+i] = (p.M[i] + CH-1)/CH;
    cnq[3+i] = (p.v[i] + QB-1)/QB;        p.cnc[3+i] = (NGT + CH-1)/CH;
    cnq[6+i] = (NSAMP + QB-1)/QB;         p.cnc[6+i] = (NGT + CH-1)/CH;
  }
  p.cseg[0] = 0;
  for (int s=0;s<9;s++) p.cseg[s+1] = p.cseg[s] + cnq[s]*p.cnc[s];

  // finish packed segments: seg = z*3 + mesh
  int fn[12];
  for (int i=0;i<3;i++){
    fn[0+i] = (p.M[i] + 255)/256;
    fn[3+i] = (NGT + 255)/256;
    fn[6+i] = (p.E[i] + 255)/256;
    fn[9+i] = (p.v[i] + 255)/256;
  }
  p.fseg[0] = 0;
  for (int s=0;s<12;s++) p.fseg[s+1] = p.fseg[s] + fn[s];

  int initB = (p.init_words + 255)/256;
  p.prep_init_blocks = initB;

  prep_kernel   <<<dim3(initB + 3*16), 256, 0, stream>>>(p);
  chamfer_kernel<<<dim3(p.cseg[9]),    256, 0, stream>>>(p);
  finish_kernel <<<dim3(p.fseg[12]),   256, 0, stream>>>(p, (float*)d_out);
}

// Round 3
// 151.580 us; speedup vs baseline: 1.2115x; 1.0167x over previous
//
#include <hip/hip_runtime.h>
#include <stdint.h>

#define NGT 8000
#define NSAMP 4000
#define QT 8         // queries per thread (register tile)
#define QB 2048      // queries per block (256 threads * QT)
#define CH 128       // scanned-points chunk per block

struct Params {
  const float* gt;        // (8000,3)
  const float* gtn;       // (8000,3)
  const float* pred[3];   // (v,3)
  const float* bef[3];    // (v,3)
  const int*   edges[3];  // (3v,2)
  const int*   faces[3];  // (2v,3)
  const int*   lap[3];    // (v,10)
  float* S[3];            // (4000,3) sampled surface points
  unsigned int* mb1[3];        // (8000) ordered-float min bits (dist1)
  unsigned long long* mb2a[3]; // (v) packed (ordered dist << 32 | gt idx) for pred queries
  unsigned int* mb2b[3];       // (4000) ordered-float min bits for sample queries
  float* acc;             // per mesh i: [8i]=sum_d1 [8i+1]=sum_d2 [8i+2]=sum|dot| [8i+3]=edge_sq [8i+4]=lap_sq [8i+5]=move_sq
  unsigned int* counter;  // finish_kernel block-completion counter
  unsigned int* init_base;// = (u32*)d_ws
  int init_words;         // words to initialize (first 64 -> 0, rest -> 0xFF)
  int prep_init_blocks;   // ceil(init_words/256)
  int v[3], M[3], E[3], F[3];
  int cseg[10];           // chamfer segment starts; seg = role*3 + mesh
  int cnc[9];             // chunks per segment
  int fseg[13];           // finish segment starts; seg = z*3 + mesh
};

// ---- ordered-float <-> uint (monotone, atomicMin-compatible) ----
__device__ __forceinline__ unsigned int ford(float f){
  unsigned int b = __float_as_uint(f);
  return b ^ ((b >> 31) ? 0xFFFFFFFFu : 0x80000000u);
}
__device__ __forceinline__ float funord(unsigned int u){
  unsigned int b = u ^ ((u >> 31) ? 0x80000000u : 0xFFFFFFFFu);
  return __uint_as_float(b);
}

// ---------------- threefry2x32 (exact JAX) ----------------
__device__ __forceinline__ uint32_t rotl32(uint32_t x, int d){ return (x<<d)|(x>>(32-d)); }

__device__ __forceinline__ void tf2x32(uint32_t k0, uint32_t k1, uint32_t c0, uint32_t c1,
                                       uint32_t& o0, uint32_t& o1){
  uint32_t ks2 = k0 ^ k1 ^ 0x1BD11BDAu;
  uint32_t x0 = c0 + k0, x1 = c1 + k1;
  x0+=x1; x1=rotl32(x1,13); x1^=x0;
  x0+=x1; x1=rotl32(x1,15); x1^=x0;
  x0+=x1; x1=rotl32(x1,26); x1^=x0;
  x0+=x1; x1=rotl32(x1, 6); x1^=x0;
  x0+=k1; x1+=ks2+1u;
  x0+=x1; x1=rotl32(x1,17); x1^=x0;
  x0+=x1; x1=rotl32(x1,29); x1^=x0;
  x0+=x1; x1=rotl32(x1,16); x1^=x0;
  x0+=x1; x1=rotl32(x1,24); x1^=x0;
  x0+=ks2; x1+=k0+2u;
  x0+=x1; x1=rotl32(x1,13); x1^=x0;
  x0+=x1; x1=rotl32(x1,15); x1^=x0;
  x0+=x1; x1=rotl32(x1,26); x1^=x0;
  x0+=x1; x1=rotl32(x1, 6); x1^=x0;
  x0+=k0; x1+=k1+3u;
  x0+=x1; x1=rotl32(x1,17); x1^=x0;
  x0+=x1; x1=rotl32(x1,29); x1^=x0;
  x0+=x1; x1=rotl32(x1,16); x1^=x0;
  x0+=x1; x1=rotl32(x1,24); x1^=x0;
  x0+=k1; x1+=ks2+4u;
  x0+=x1; x1=rotl32(x1,13); x1^=x0;
  x0+=x1; x1=rotl32(x1,15); x1^=x0;
  x0+=x1; x1=rotl32(x1,26); x1^=x0;
  x0+=x1; x1=rotl32(x1, 6); x1^=x0;
  x0+=ks2; x1+=k0+5u;
  o0=x0; o1=x1;
}

__device__ __forceinline__ uint32_t rbits(uint32_t k0, uint32_t k1, uint32_t idx, uint32_t total){
  uint32_t half = total>>1, o0, o1;
  if (idx < half){ tf2x32(k0,k1, idx, idx+half, o0, o1); return o0; }
  tf2x32(k0,k1, idx-half, idx, o0, o1); return o1;
}

// ---------------- A: init workspace + sample surface points (1D packed) ----------------
__global__ __launch_bounds__(256) void prep_kernel(Params p){
  int b = blockIdx.x;
  int t = threadIdx.x;
  if (b < p.prep_init_blocks){
    int wdi = b*256 + t;
    if (wdi < p.init_words)
      p.init_base[wdi] = (wdi < 64) ? 0u : 0xFFFFFFFFu;
    return;
  }
  int rem = b - p.prep_init_blocks;   // 16 sample blocks per mesh
  int i = rem >> 4;
  int s = ((rem & 15) << 8) + t;
  if (s >= NSAMP) return;
  uint32_t bk0, bk1; tf2x32(0u, 42u, 0u, (uint32_t)i, bk0, bk1);
  uint32_t ka0,kb0,ka1,kb1;
  tf2x32(bk0,bk1, 0u,2u, ka0,kb0);
  tf2x32(bk0,bk1, 1u,3u, ka1,kb1);
  uint32_t fb = rbits(ka0,ka1,(uint32_t)s, NSAMP);
  uint32_t fidx = fb % (uint32_t)p.F[i];
  uint32_t u0b = rbits(kb0,kb1, 2u*(uint32_t)s,    2u*NSAMP);
  uint32_t u1b = rbits(kb0,kb1, 2u*(uint32_t)s+1u, 2u*NSAMP);
  float u0 = __uint_as_float((u0b>>9)|0x3F800000u) - 1.0f;
  float u1 = __uint_as_float((u1b>>9)|0x3F800000u) - 1.0f;
  float r1 = sqrtf(u0);
  float w0 = 1.0f - r1, w1 = r1*(1.0f-u1), w2 = r1*u1;
  const int* f = p.faces[i] + 3*(int)fidx;
  const float* pr = p.pred[i];
  int va=f[0], vb=f[1], vc=f[2];
  float* dst = p.S[i] + 3*s;
  dst[0] = w0*pr[3*va+0] + w1*pr[3*vb+0] + w2*pr[3*vc+0];
  dst[1] = w0*pr[3*va+1] + w1*pr[3*vb+1] + w2*pr[3*vc+1];
  dst[2] = w0*pr[3*va+2] + w1*pr[3*vb+2] + w2*pr[3*vc+2];
}

// ---------------- B: fused chamfer, packed 1D grid, 3 roles ----------------
__device__ __forceinline__ float dist_e(const float4 g, float qx, float qy, float qz){
  return fmaf(g.x,qx, fmaf(g.y,qy, fmaf(g.z,qz, g.w)));
}

// min-only scan: 8-point register groups; 8 ds_read then 224 VALU
__device__ __forceinline__ void scan_min(const float4* __restrict__ tile, int lim,
    const float* qx, const float* qy, const float* qz, float* best)
{
  int k = 0;
  int lim8 = lim & ~7;
  for (; k < lim8; k += 8){
    float4 g0=tile[k+0],g1=tile[k+1],g2=tile[k+2],g3=tile[k+3];
    float4 g4=tile[k+4],g5=tile[k+5],g6=tile[k+6],g7=tile[k+7];
    #pragma unroll
    for (int q=0;q<QT;q++){
      float d0=dist_e(g0,qx[q],qy[q],qz[q]);
      float d1=dist_e(g1,qx[q],qy[q],qz[q]);
      float d2=dist_e(g2,qx[q],qy[q],qz[q]);
      float d3=dist_e(g3,qx[q],qy[q],qz[q]);
      float d4=dist_e(g4,qx[q],qy[q],qz[q]);
      float d5=dist_e(g5,qx[q],qy[q],qz[q]);
      float d6=dist_e(g6,qx[q],qy[q],qz[q]);
      float d7=dist_e(g7,qx[q],qy[q],qz[q]);
      float m = fminf(fminf(best[q], d0), d1);  // -> v_min3_f32 chains
      m = fminf(fminf(m, d2), d3);
      m = fminf(fminf(m, d4), d5);
      m = fminf(fminf(m, d6), d7);
      best[q] = m;
    }
  }
  for (; k < lim; k++){
    float4 g = tile[k];
    #pragma unroll
    for (int q=0;q<QT;q++)
      best[q] = fminf(best[q], dist_e(g,qx[q],qy[q],qz[q]));
  }
}

// argmin scan: ascending k + strict '<' keeps first occurrence (JAX argmin semantics)
__device__ __forceinline__ void scan_argmin(const float4* __restrict__ tile, int lim, int c0,
    const float* qx, const float* qy, const float* qz, float* best, int* bidx)
{
  int k = 0;
  int lim4 = lim & ~3;
  for (; k < lim4; k += 4){
    float4 g0=tile[k+0],g1=tile[k+1],g2=tile[k+2],g3=tile[k+3];
    #pragma unroll
    for (int q=0;q<QT;q++){
      float d0=dist_e(g0,qx[q],qy[q],qz[q]);
      float d1=dist_e(g1,qx[q],qy[q],qz[q]);
      float d2=dist_e(g2,qx[q],qy[q],qz[q]);
      float d3=dist_e(g3,qx[q],qy[q],qz[q]);
      if (d0 < best[q]){ best[q]=d0; bidx[q]=c0+k+0; }
      if (d1 < best[q]){ best[q]=d1; bidx[q]=c0+k+1; }
      if (d2 < best[q]){ best[q]=d2; bidx[q]=c0+k+2; }
      if (d3 < best[q]){ best[q]=d3; bidx[q]=c0+k+3; }
    }
  }
  for (; k < lim; k++){
    float4 g = tile[k];
    #pragma unroll
    for (int q=0;q<QT;q++){
      float d = dist_e(g,qx[q],qy[q],qz[q]);
      if (d < best[q]){ best[q]=d; bidx[q]=c0+k; }
    }
  }
}

// role 0: dist1      — queries = gt (8000),  scan P=pred++S chunk
// role 1: dist2-pred — queries = pred (v),   scan gt chunk, argmin tracked
// role 2: dist2-samp — queries = S (4000),   scan gt chunk, min only
__global__ __launch_bounds__(256) void chamfer_kernel(Params p){
  __shared__ float4 tile[CH];
  int b = blockIdx.x;
  int seg = 0;
  #pragma unroll
  for (int s=1;s<9;s++) seg += (b >= p.cseg[s]) ? 1 : 0;
  int rem  = b - p.cseg[seg];
  int nc   = p.cnc[seg];
  int cq   = rem / nc;
  int cc   = rem - cq*nc;
  int role = seg / 3;
  int i    = seg - role*3;
  int t = threadIdx.x;
  int qbase = cq*QB;
  int c0 = cc*CH;
  int v = p.v[i];

  if (role == 0){
    int M = p.M[i];
    int lim = min(M - c0, CH);
    if (t < lim){
      int j = c0 + t;
      const float* src = (j < v) ? (p.pred[i] + 3*j) : (p.S[i] + 3*(j-v));
      float x=src[0], y=src[1], z=src[2];
      tile[t] = make_float4(x,y,z, x*x+y*y+z*z);
    }
    float qx[QT],qy[QT],qz[QT],qs[QT],best[QT];
    #pragma unroll
    for (int k=0;k<QT;k++){
      int q = qbase + t + k*256;
      float x=0.f,y=0.f,z=0.f;
      if (q < NGT){ x=p.gt[3*q]; y=p.gt[3*q+1]; z=p.gt[3*q+2]; }
      qs[k]=x*x+y*y+z*z; qx[k]=-2.f*x; qy[k]=-2.f*y; qz[k]=-2.f*z;
      best[k]=3.4e38f;
    }
    __syncthreads();
    scan_min(tile, lim, qx,qy,qz,best);
    #pragma unroll
    for (int k=0;k<QT;k++){
      int q = qbase + t + k*256;
      if (q < NGT) atomicMin(&p.mb1[i][q], ford(best[k]+qs[k]));
    }
  } else if (role == 1){
    int lim = min(NGT - c0, CH);
    if (t < lim){
      int j = c0 + t;
      float x=p.gt[3*j], y=p.gt[3*j+1], z=p.gt[3*j+2];
      tile[t] = make_float4(x,y,z, x*x+y*y+z*z);
    }
    float qx[QT],qy[QT],qz[QT],qs[QT],best[QT];
    int bidx[QT];
    #pragma unroll
    for (int k=0;k<QT;k++){
      int q = qbase + t + k*256;
      float x=0.f,y=0.f,z=0.f;
      if (q < v){
        const float* src = p.pred[i] + 3*q;
        x=src[0]; y=src[1]; z=src[2];
      }
      qs[k]=x*x+y*y+z*z; qx[k]=-2.f*x; qy[k]=-2.f*y; qz[k]=-2.f*z;
      best[k]=3.4e38f; bidx[k]=0;
    }
    __syncthreads();
    scan_argmin(tile, lim, c0, qx,qy,qz,best,bidx);
    #pragma unroll
    for (int k=0;k<QT;k++){
      int q = qbase + t + k*256;
      if (q < v){
        unsigned long long pk = ((unsigned long long)ford(best[k]+qs[k])<<32) | (unsigned int)bidx[k];
        atomicMin(&p.mb2a[i][q], pk);   // equal dist -> smaller gt idx = first occurrence
      }
    }
  } else {
    int lim = min(NGT - c0, CH);
    if (t < lim){
      int j = c0 + t;
      float x=p.gt[3*j], y=p.gt[3*j+1], z=p.gt[3*j+2];
      tile[t] = make_float4(x,y,z, x*x+y*y+z*z);
    }
    float qx[QT],qy[QT],qz[QT],qs[QT],best[QT];
    #pragma unroll
    for (int k=0;k<QT;k++){
      int q = qbase + t + k*256;
      float x=0.f,y=0.f,z=0.f;
      if (q < NSAMP){
        const float* src = p.S[i] + 3*q;
        x=src[0]; y=src[1]; z=src[2];
      }
      qs[k]=x*x+y*y+z*z; qx[k]=-2.f*x; qy[k]=-2.f*y; qz[k]=-2.f*z;
      best[k]=3.4e38f;
    }
    __syncthreads();
    scan_min(tile, lim, qx,qy,qz,best);
    #pragma unroll
    for (int k=0;k<QT;k++){
      int q = qbase + t + k*256;
      if (q < NSAMP) atomicMin(&p.mb2b[i][q], ford(best[k]+qs[k]));
    }
  }
}

// ---------------- C: reductions + losses + last-block finalize (1D packed) ----------------
// z=0: dist2 sum over M; z=1: dist1 sum over NGT; z=2: edge+normal over E; z=3: lap+move over v
__global__ __launch_bounds__(256) void finish_kernel(Params p, float* out){
  __shared__ float red[256];
  int b = blockIdx.x;
  int seg = 0;
  #pragma unroll
  for (int s=1;s<12;s++) seg += (b >= p.fseg[s]) ? 1 : 0;
  int rem = b - p.fseg[seg];
  int z = seg / 3;
  int i = seg - 3*z;
  int tid = threadIdx.x;
  int gidx = rem*256 + tid;

  if (z == 0){
    int M = p.M[i], v = p.v[i];
    float val = 0.f;
    if (gidx < M){
      if (gidx < v) val = funord((unsigned int)(p.mb2a[i][gidx]>>32));
      else          val = funord(p.mb2b[i][gidx-v]);
    }
    red[tid] = val; __syncthreads();
    for (int s=128;s>0;s>>=1){ if (tid<s) red[tid]+=red[tid+s]; __syncthreads(); }
    if (tid==0 && red[0]!=0.f) atomicAdd(&p.acc[8*i+1], red[0]);
  } else if (z == 1){
    float val = 0.f;
    if (gidx < NGT) val = funord(p.mb1[i][gidx]);
    red[tid] = val; __syncthreads();
    for (int s=128;s>0;s>>=1){ if (tid<s) red[tid]+=red[tid+s]; __syncthreads(); }
    if (tid==0 && red[0]!=0.f) atomicAdd(&p.acc[8*i+0], red[0]);
  } else if (z == 2){
    int E = p.E[i];
    float sq = 0.f, ad = 0.f;
    if (gidx < E){
      int e0 = p.edges[i][2*gidx], e1 = p.edges[i][2*gidx+1];
      const float* pr = p.pred[i];
      float dx = pr[3*e0+0]-pr[3*e1+0];
      float dy = pr[3*e0+1]-pr[3*e1+1];
      float dz = pr[3*e0+2]-pr[3*e1+2];
      sq = dx*dx+dy*dy+dz*dz;
      float inv = 1.0f / fmaxf(sqrtf(sq), 1e-12f);
      int g = (int)(unsigned int)p.mb2a[i][e0];   // argmin gt index (low 32 bits)
      float nx = p.gtn[3*g+0], ny = p.gtn[3*g+1], nz = p.gtn[3*g+2];
      float invg = 1.0f / fmaxf(sqrtf(nx*nx+ny*ny+nz*nz), 1e-12f);
      ad = fabsf((dx*nx+dy*ny+dz*nz)*inv*invg);
    }
    red[tid] = ad; __syncthreads();
    for (int s=128;s>0;s>>=1){ if (tid<s) red[tid]+=red[tid+s]; __syncthreads(); }
    if (tid==0 && red[0]!=0.f) atomicAdd(&p.acc[8*i+2], red[0]);
    __syncthreads();
    red[tid] = sq; __syncthreads();
    for (int s=128;s>0;s>>=1){ if (tid<s) red[tid]+=red[tid+s]; __syncthreads(); }
    if (tid==0 && red[0]!=0.f) atomicAdd(&p.acc[8*i+3], red[0]);
  } else {
    int v = p.v[i];
    float lsq = 0.f, msq = 0.f;
    if (gidx < v){
      const int* L = p.lap[i] + 10*gidx;
      const float* B = p.bef[i];
      const float* R = p.pred[i];
      float cnt = (float)L[9];
      float sb0=0,sb1=0,sb2=0, sp0=0,sp1=0,sp2=0;
      #pragma unroll
      for (int k=0;k<8;k++){
        int id = L[k];
        if (id >= 0){
          sb0 += B[3*id+0]; sb1 += B[3*id+1]; sb2 += B[3*id+2];
          sp0 += R[3*id+0]; sp1 += R[3*id+1]; sp2 += R[3*id+2];
        }
      }
      float lb0 = B[3*gidx+0] - sb0/cnt, lb1 = B[3*gidx+1] - sb1/cnt, lb2 = B[3*gidx+2] - sb2/cnt;
      float lp0 = R[3*gidx+0] - sp0/cnt, lp1 = R[3*gidx+1] - sp1/cnt, lp2 = R[3*gidx+2] - sp2/cnt;
      float d0=lb0-lp0, d1=lb1-lp1, d2=lb2-lp2;
      lsq = d0*d0+d1*d1+d2*d2;
      float m0=B[3*gidx+0]-R[3*gidx+0], m1=B[3*gidx+1]-R[3*gidx+1], m2=B[3*gidx+2]-R[3*gidx+2];
      msq = m0*m0+m1*m1+m2*m2;
    }
    red[tid] = lsq; __syncthreads();
    for (int s=128;s>0;s>>=1){ if (tid<s) red[tid]+=red[tid+s]; __syncthreads(); }
    if (tid==0 && red[0]!=0.f) atomicAdd(&p.acc[8*i+4], red[0]);
    __syncthreads();
    red[tid] = msq; __syncthreads();
    for (int s=128;s>0;s>>=1){ if (tid<s) red[tid]+=red[tid+s]; __syncthreads(); }
    if (tid==0 && red[0]!=0.f) atomicAdd(&p.acc[8*i+5], red[0]);
  }

  __syncthreads();
  if (tid == 0){
    __threadfence();
    unsigned int total = gridDim.x;
    unsigned int old = atomicAdd(p.counter, 1u);
    if (old == total-1){
      __threadfence();
      const float CHAMW[3] = {3000.0f, 3000.0f, 3000.0f};
      const float LAPC[3]  = {0.2f, 1.0f, 1.0f};
      float loss = 0.0f;
      for (int m=0;m<3;m++){
        float a0 = __hip_atomic_load(&p.acc[8*m+0], __ATOMIC_RELAXED, __HIP_MEMORY_SCOPE_AGENT);
        float a1 = __hip_atomic_load(&p.acc[8*m+1], __ATOMIC_RELAXED, __HIP_MEMORY_SCOPE_AGENT);
        float a2 = __hip_atomic_load(&p.acc[8*m+2], __ATOMIC_RELAXED, __HIP_MEMORY_SCOPE_AGENT);
        float a3 = __hip_atomic_load(&p.acc[8*m+3], __ATOMIC_RELAXED, __HIP_MEMORY_SCOPE_AGENT);
        float a4 = __hip_atomic_load(&p.acc[8*m+4], __ATOMIC_RELAXED, __HIP_MEMORY_SCOPE_AGENT);
        float a5 = __hip_atomic_load(&p.acc[8*m+5], __ATOMIC_RELAXED, __HIP_MEMORY_SCOPE_AGENT);
        float ch = CHAMW[m]*(a0/(float)NGT + 0.55f*a1/(float)p.M[m]);
        float nl = a2/(float)p.E[m];
        float el = a3/(float)p.E[m];
        float ll = LAPC[m]*a4/(float)p.v[m];
        float ml = (m>0) ? LAPC[m]*a5/(float)p.v[m] : 0.0f;
        loss += ch + 1500.0f*ll + 50.0f*ml + 359.0f*el + 0.5f*nl;
      }
      out[0] = loss;
    }
  }
}

extern "C" void kernel_launch(void* const* d_in, const int* in_sizes, int n_in,
                              void* d_out, int out_size, void* d_ws, size_t ws_size,
                              hipStream_t stream) {
  Params p;
  p.gt  = (const float*)d_in[0];
  p.gtn = (const float*)d_in[1];
  for (int i=0;i<3;i++){
    p.pred[i]  = (const float*)d_in[2+5*i];
    p.bef[i]   = (const float*)d_in[3+5*i];
    p.edges[i] = (const int*)  d_in[4+5*i];
    p.faces[i] = (const int*)  d_in[5+5*i];
    p.lap[i]   = (const int*)  d_in[6+5*i];
    p.v[i] = in_sizes[2+5*i]/3;
    p.E[i] = in_sizes[4+5*i]/2;
    p.F[i] = in_sizes[5+5*i]/3;
    p.M[i] = p.v[i] + NSAMP;
  }
  // Workspace layout (words):
  //   [0,32)  acc  (zeroed)
  //   [32]    counter (zeroed; zero-region = first 64 words)
  //   [64..)  mb1[3] | mb2a[3] | mb2b[3]   (0xFF-filled)
  //   then    S[3]  (written by prep, no init)
  unsigned int* base = (unsigned int*)d_ws;
  p.acc = (float*)base;
  p.counter = base + 32;
  p.init_base = base;
  unsigned int* w = base + 64;
  for (int i=0;i<3;i++){ p.mb1[i]  = w; w += NGT; }
  for (int i=0;i<3;i++){ p.mb2a[i] = (unsigned long long*)w; w += 2*p.v[i]; }
  for (int i=0;i<3;i++){ p.mb2b[i] = w; w += NSAMP; }
  p.init_words = (int)(w - base);
  for (int i=0;i<3;i++){ p.S[i] = (float*)w; w += NSAMP*3; }

  // chamfer packed segments: seg = role*3 + mesh
  int cnq[9];
  for (int i=0;i<3;i++){
    cnq[0+i] = (NGT + QB-1)/QB;           p.cnc[0+i] = (p.M[i] + CH-1)/CH;
    cnq[3+i] = (p.v[i] + QB-1)/QB;        p.cnc[3+i] = (NGT + CH-1)/CH;
    cnq[6+i] = (NSAMP + QB-1)/QB;         p.cnc[6+i] = (NGT + CH-1)/CH;
  }
  p.cseg[0] = 0;
  for (int s=0;s<9;s++) p.cseg[s+1] = p.cseg[s] + cnq[s]*p.cnc[s];

  // finish packed segments: seg = z*3 + mesh
  int fn[12];
  for (int i=0;i<3;i++){
    fn[0+i] = (p.M[i] + 255)/256;
    fn[3+i] = (NGT + 255)/256;
    fn[6+i] = (p.E[i] + 255)/256;
    fn[9+i] = (p.v[i] + 255)/256;
  }
  p.fseg[0] = 0;
  for (int s=0;s<12;s++) p.fseg[s+1] = p.fseg[s] + fn[s];

  int initB = (p.init_words + 255)/256;
  p.prep_init_blocks = initB;

  prep_kernel   <<<dim3(initB + 3*16), 256, 0, stream>>>(p);
  chamfer_kernel<<<dim3(p.cseg[9]),    256, 0, stream>>>(p);
  finish_kernel <<<dim3(p.fseg[12]),   256, 0, stream>>>(p, (float*)d_out);
}